// Round 1
// baseline (1379.649 us; speedup 1.0000x reference)
//
#include <hip/hip_runtime.h>

// MNIST_RNN: 2-layer LSTM (H=10, D=28, T=28) + linear classifier, fp32.
// Strategy: 2 threads per sample (5 hidden units each) -> 65536 threads =
// 1024 waves = 1 wave/SIMD across 256 CUs. Weights staged in LDS (broadcast
// reads, 2 distinct addresses/wave = free). x rows loaded as float4 by both
// lanes of a pair (identical addresses dedupe in L1/L2). h exchanged between
// the pair via __shfl_xor(.,1).

#define HDIM 10
#define DDIM 28
#define TSTEPS 28
#define GDIM 40        // 4*H
#define WLD 12         // padded leading dim for H=10 rows (16B-aligned rows)

__device__ __forceinline__ float fast_sigmoid(float v) {
    return __builtin_amdgcn_rcpf(1.0f + __expf(-v));
}
__device__ __forceinline__ float fast_tanh(float v) {
    // tanh(x) = 2*sigmoid(2x) - 1
    return 2.0f * __builtin_amdgcn_rcpf(1.0f + __expf(-2.0f * v)) - 1.0f;
}

__global__ __launch_bounds__(256) void lstm2_cls_kernel(
    const float* __restrict__ x,
    const float* __restrict__ w_ih0, const float* __restrict__ w_hh0,
    const float* __restrict__ b_ih0, const float* __restrict__ b_hh0,
    const float* __restrict__ w_ih1, const float* __restrict__ w_hh1,
    const float* __restrict__ b_ih1, const float* __restrict__ b_hh1,
    const float* __restrict__ w_cls, const float* __restrict__ b_cls,
    float* __restrict__ out, int B)
{
    __shared__ float s_wih0[GDIM * DDIM];   // [40][28]
    __shared__ float s_whh0[GDIM * WLD];    // [40][12] (cols 10,11 = 0)
    __shared__ float s_wih1[GDIM * WLD];    // [40][12]
    __shared__ float s_whh1[GDIM * WLD];    // [40][12]
    __shared__ float s_b0[GDIM];            // b_ih0 + b_hh0
    __shared__ float s_b1[GDIM];            // b_ih1 + b_hh1
    __shared__ float s_wcls[10 * WLD];      // [10][12]
    __shared__ float s_bcls[10];

    const int tid = threadIdx.x;

    for (int i = tid; i < GDIM * DDIM; i += 256) s_wih0[i] = w_ih0[i];
    for (int i = tid; i < GDIM * WLD; i += 256) {
        int r = i / WLD, c = i % WLD;
        float vh0 = (c < HDIM) ? w_hh0[r * HDIM + c] : 0.0f;
        float vi1 = (c < HDIM) ? w_ih1[r * HDIM + c] : 0.0f;
        float vh1 = (c < HDIM) ? w_hh1[r * HDIM + c] : 0.0f;
        s_whh0[i] = vh0; s_wih1[i] = vi1; s_whh1[i] = vh1;
    }
    for (int i = tid; i < GDIM; i += 256) {
        s_b0[i] = b_ih0[i] + b_hh0[i];
        s_b1[i] = b_ih1[i] + b_hh1[i];
    }
    for (int i = tid; i < 10 * WLD; i += 256) {
        int r = i / WLD, c = i % WLD;
        s_wcls[i] = (c < HDIM) ? w_cls[r * HDIM + c] : 0.0f;
    }
    for (int i = tid; i < 10; i += 256) s_bcls[i] = b_cls[i];
    __syncthreads();

    const int gtid = blockIdx.x * 256 + tid;
    const int sample = gtid >> 1;
    if (sample >= B) return;
    const int half = gtid & 1;        // 0: units 0..4, 1: units 5..9
    const int ubase = half * 5;

    const float* xrow = x + (size_t)sample * (TSTEPS * DDIM);

    // Full h (both halves, post-exchange) + own-c state
    float h0A[5], h0B[5], c0[5];
    float h1A[5], h1B[5], c1[5];
    #pragma unroll
    for (int k = 0; k < 5; ++k) {
        h0A[k] = h0B[k] = c0[k] = 0.0f;
        h1A[k] = h1B[k] = c1[k] = 0.0f;
    }

    #pragma unroll 1
    for (int t = 0; t < TSTEPS; ++t) {
        // x[sample, t, :] as 7 x float4 (offsets are 16B aligned: 112*t, 3136*s)
        float xr[DDIM];
        const float4* xp = (const float4*)(xrow + t * DDIM);
        #pragma unroll
        for (int v = 0; v < 7; ++v) {
            float4 q = xp[v];
            xr[4*v+0] = q.x; xr[4*v+1] = q.y; xr[4*v+2] = q.z; xr[4*v+3] = q.w;
        }

        // ------------- layer 0 -------------
        float acc0[4][5];
        #pragma unroll
        for (int q = 0; q < 4; ++q) {
            #pragma unroll
            for (int k = 0; k < 5; ++k) {
                const int r = q * HDIM + ubase + k;
                float a = s_b0[r];
                const float* wi = &s_wih0[r * DDIM];
                #pragma unroll
                for (int d = 0; d < DDIM; ++d) a += xr[d] * wi[d];
                const float* wh = &s_whh0[r * WLD];
                #pragma unroll
                for (int j = 0; j < 5; ++j) a += h0A[j] * wh[j];
                #pragma unroll
                for (int j = 0; j < 5; ++j) a += h0B[j] * wh[5 + j];
                acc0[q][k] = a;
            }
        }
        float hown0[5];
        #pragma unroll
        for (int k = 0; k < 5; ++k) {
            float ig = fast_sigmoid(acc0[0][k]);
            float fg = fast_sigmoid(acc0[1][k]);
            float gg = fast_tanh(acc0[2][k]);
            float og = fast_sigmoid(acc0[3][k]);
            float c = fg * c0[k] + ig * gg;
            c0[k] = c;
            hown0[k] = og * fast_tanh(c);
        }
        #pragma unroll
        for (int k = 0; k < 5; ++k) {
            float p = __shfl_xor(hown0[k], 1);
            h0A[k] = half ? p : hown0[k];
            h0B[k] = half ? hown0[k] : p;
        }

        // ------------- layer 1 ------------- input = h0 (current t)
        float acc1[4][5];
        #pragma unroll
        for (int q = 0; q < 4; ++q) {
            #pragma unroll
            for (int k = 0; k < 5; ++k) {
                const int r = q * HDIM + ubase + k;
                float a = s_b1[r];
                const float* wi = &s_wih1[r * WLD];
                #pragma unroll
                for (int j = 0; j < 5; ++j) a += h0A[j] * wi[j];
                #pragma unroll
                for (int j = 0; j < 5; ++j) a += h0B[j] * wi[5 + j];
                const float* wh = &s_whh1[r * WLD];
                #pragma unroll
                for (int j = 0; j < 5; ++j) a += h1A[j] * wh[j];
                #pragma unroll
                for (int j = 0; j < 5; ++j) a += h1B[j] * wh[5 + j];
                acc1[q][k] = a;
            }
        }
        float hown1[5];
        #pragma unroll
        for (int k = 0; k < 5; ++k) {
            float ig = fast_sigmoid(acc1[0][k]);
            float fg = fast_sigmoid(acc1[1][k]);
            float gg = fast_tanh(acc1[2][k]);
            float og = fast_sigmoid(acc1[3][k]);
            float c = fg * c1[k] + ig * gg;
            c1[k] = c;
            hown1[k] = og * fast_tanh(c);
        }
        #pragma unroll
        for (int k = 0; k < 5; ++k) {
            float p = __shfl_xor(hown1[k], 1);
            h1A[k] = half ? p : hown1[k];
            h1B[k] = half ? hown1[k] : p;
        }
    }

    // ------------- classifier: out[sample, ubase..ubase+4] -------------
    #pragma unroll
    for (int k = 0; k < 5; ++k) {
        const int o = ubase + k;
        float a = s_bcls[o];
        const float* wc = &s_wcls[o * WLD];
        #pragma unroll
        for (int j = 0; j < 5; ++j) a += h1A[j] * wc[j];
        #pragma unroll
        for (int j = 0; j < 5; ++j) a += h1B[j] * wc[5 + j];
        out[(size_t)sample * 10 + o] = a;
    }
}

extern "C" void kernel_launch(void* const* d_in, const int* in_sizes, int n_in,
                              void* d_out, int out_size, void* d_ws, size_t ws_size,
                              hipStream_t stream) {
    const float* x     = (const float*)d_in[0];
    const float* w_ih0 = (const float*)d_in[1];
    const float* w_hh0 = (const float*)d_in[2];
    const float* b_ih0 = (const float*)d_in[3];
    const float* b_hh0 = (const float*)d_in[4];
    const float* w_ih1 = (const float*)d_in[5];
    const float* w_hh1 = (const float*)d_in[6];
    const float* b_ih1 = (const float*)d_in[7];
    const float* b_hh1 = (const float*)d_in[8];
    const float* w_cls = (const float*)d_in[9];
    const float* b_cls = (const float*)d_in[10];
    float* out = (float*)d_out;

    const int B = in_sizes[0] / (TSTEPS * DDIM);   // 32768
    const int threads = B * 2;                     // 2 threads per sample
    const int block = 256;
    const int grid = (threads + block - 1) / block;

    hipLaunchKernelGGL(lstm2_cls_kernel, dim3(grid), dim3(block), 0, stream,
                       x, w_ih0, w_hh0, b_ih0, b_hh0,
                       w_ih1, w_hh1, b_ih1, b_hh1,
                       w_cls, b_cls, out, B);
}

// Round 2
// 586.352 us; speedup vs baseline: 2.3529x; 2.3529x over previous
//
#include <hip/hip_runtime.h>

// MNIST_RNN: 2-layer LSTM (H=10, D=28, T=28) + classifier, fp32.
// R2: (a) gate-at-a-time compute (5 live accs) to kill the xr[28] scratch
// spill seen in R1 (VGPR=256, WRITE_SIZE=210MB); (b) x staged per-t into
// double-buffered LDS via global_load_lds width=16 (coalesced, zero VGPR
// cost, prefetch t+1 during compute of t); (c) parity-swizzled weight
// copies in LDS so all weight reads are 2-address broadcasts, no cndmask.

#define HDIM 10
#define DDIM 28
#define TSTEPS 28
#define GDIM 40
#define WLD 12
#define SMP 128            // samples per block (block = 256 threads, 2/sample)
#define XSLOTS 896         // SMP*DDIM/4 float4 slots per t-tile

typedef const __attribute__((address_space(1))) unsigned int gu32;
typedef __attribute__((address_space(3))) unsigned int lu32;

__device__ __forceinline__ void gld_lds16(const float* g, float4* l) {
    __builtin_amdgcn_global_load_lds((gu32*)g, (lu32*)l, 16, 0, 0);
}

__device__ __forceinline__ float fast_sigmoid(float v) {
    return __builtin_amdgcn_rcpf(1.0f + __expf(-v));
}
__device__ __forceinline__ float fast_tanh(float v) {
    return 2.0f * __builtin_amdgcn_rcpf(1.0f + __expf(-2.0f * v)) - 1.0f;
}

// 5 rows of one gate, layer 0: dst[k] = b + x.Wih + h0.Whh
#define L0_GATE(dst, q) do {                                              \
    _Pragma("unroll")                                                     \
    for (int k = 0; k < 5; ++k) {                                         \
        const int r = (q)*HDIM + ubase + k;                               \
        float a = s_b0[r];                                                \
        const float* wi = &s_wih0[r*DDIM];                                \
        _Pragma("unroll")                                                 \
        for (int d = 0; d < DDIM; ++d) a += xr[d]*wi[d];                  \
        const float* wh = &s_whh0[(par*GDIM + r)*WLD];                    \
        _Pragma("unroll")                                                 \
        for (int j = 0; j < 5; ++j) a += hO0[j]*wh[j] + hP0[j]*wh[5+j];   \
        dst[k] = a;                                                       \
    } } while (0)

// 5 rows of one gate, layer 1: dst[k] = b + h0.Wih + h1.Whh
#define L1_GATE(dst, q) do {                                              \
    _Pragma("unroll")                                                     \
    for (int k = 0; k < 5; ++k) {                                         \
        const int r = (q)*HDIM + ubase + k;                               \
        float a = s_b1[r];                                                \
        const float* wi = &s_wih1[(par*GDIM + r)*WLD];                    \
        _Pragma("unroll")                                                 \
        for (int j = 0; j < 5; ++j) a += hO0[j]*wi[j] + hP0[j]*wi[5+j];   \
        const float* wh = &s_whh1[(par*GDIM + r)*WLD];                    \
        _Pragma("unroll")                                                 \
        for (int j = 0; j < 5; ++j) a += hO1[j]*wh[j] + hP1[j]*wh[5+j];   \
        dst[k] = a;                                                       \
    } } while (0)

__global__ __launch_bounds__(256) void lstm2_cls_kernel(
    const float* __restrict__ x,
    const float* __restrict__ w_ih0, const float* __restrict__ w_hh0,
    const float* __restrict__ b_ih0, const float* __restrict__ b_hh0,
    const float* __restrict__ w_ih1, const float* __restrict__ w_hh1,
    const float* __restrict__ b_ih1, const float* __restrict__ b_hh1,
    const float* __restrict__ w_cls, const float* __restrict__ b_cls,
    float* __restrict__ out, int B)
{
    __shared__ float s_wih0[GDIM * DDIM];       // [40][28], parity-independent
    __shared__ float s_whh0[2 * GDIM * WLD];    // [2 parity][40][12]
    __shared__ float s_wih1[2 * GDIM * WLD];
    __shared__ float s_whh1[2 * GDIM * WLD];
    __shared__ float s_b0[GDIM], s_b1[GDIM];
    __shared__ float s_wcls[2 * 10 * WLD];
    __shared__ float s_bcls[16];
    __shared__ float4 s_x4[2][XSLOTS];          // double-buffered x tiles

    const int tid = threadIdx.x;
    const int b0 = blockIdx.x * SMP;

    // ---- issue x preload for t=0 first (longest latency, fire-and-forget)
    const float* gsrc[4];
    #pragma unroll
    for (int k = 0; k < 4; ++k) {
        const int id = tid + 256*k;
        const int chunk = id / 7, v = id - 7*chunk;
        gsrc[k] = x + (size_t)(b0 + chunk) * (TSTEPS*DDIM) + 4*v;
    }
    #pragma unroll
    for (int k = 0; k < 3; ++k) gld_lds16(gsrc[k], &s_x4[0][tid + 256*k]);
    if (tid < 128) gld_lds16(gsrc[3], &s_x4[0][tid + 768]);

    // ---- stage weights (parity-swizzled copies: col j<5 = own units,
    //      col 5+j = partner units; even lane own=0..4, odd own=5..9)
    for (int i = tid; i < GDIM*DDIM; i += 256) s_wih0[i] = w_ih0[i];
    for (int i = tid; i < 2*GDIM*WLD; i += 256) {
        const int p = i / (GDIM*WLD), rem = i - p*(GDIM*WLD);
        const int r = rem / WLD, c = rem - r*WLD;
        const int oc = (c < 5) ? (p ? c+5 : c) : ((c < 10) ? (p ? c-5 : c) : -1);
        s_whh0[i] = (oc >= 0) ? w_hh0[r*HDIM+oc] : 0.0f;
        s_wih1[i] = (oc >= 0) ? w_ih1[r*HDIM+oc] : 0.0f;
        s_whh1[i] = (oc >= 0) ? w_hh1[r*HDIM+oc] : 0.0f;
    }
    for (int i = tid; i < GDIM; i += 256) {
        s_b0[i] = b_ih0[i] + b_hh0[i];
        s_b1[i] = b_ih1[i] + b_hh1[i];
    }
    for (int i = tid; i < 2*10*WLD; i += 256) {
        const int p = i / (10*WLD), rem = i - p*(10*WLD);
        const int r = rem / WLD, c = rem - r*WLD;
        const int oc = (c < 5) ? (p ? c+5 : c) : ((c < 10) ? (p ? c-5 : c) : -1);
        s_wcls[i] = (oc >= 0) ? w_cls[r*HDIM+oc] : 0.0f;
    }
    if (tid < 10) s_bcls[tid] = b_cls[tid];
    __syncthreads();   // drains weight ds_writes AND the t=0 x DMA (vmcnt)

    const int par = tid & 1;
    const int ubase = par * 5;
    const int sl = tid >> 1;            // sample within block
    const int sample = b0 + sl;

    float hO0[5], hP0[5], c0[5], hO1[5], hP1[5], c1[5];
    #pragma unroll
    for (int k = 0; k < 5; ++k) {
        hO0[k]=hP0[k]=c0[k]=0.0f; hO1[k]=hP1[k]=c1[k]=0.0f;
    }

    #pragma unroll 1
    for (int t = 0; t < TSTEPS; ++t) {
        const int cur = t & 1;

        // prefetch tile t+1 into the other buffer (zero-VGPR DMA)
        if (t + 1 < TSTEPS) {
            #pragma unroll
            for (int k = 0; k < 3; ++k) {
                gsrc[k] += DDIM;
                gld_lds16(gsrc[k], &s_x4[cur^1][tid + 256*k]);
            }
            if (tid < 128) {
                gsrc[3] += DDIM;
                gld_lds16(gsrc[3], &s_x4[cur^1][tid + 768]);
            }
        }

        // x row for this sample, from LDS (7x ds_read_b128)
        float xr[DDIM];
        {
            const float4* xp = &s_x4[cur][sl * 7];
            #pragma unroll
            for (int v = 0; v < 7; ++v) {
                const float4 q = xp[v];
                xr[4*v+0]=q.x; xr[4*v+1]=q.y; xr[4*v+2]=q.z; xr[4*v+3]=q.w;
            }
        }

        // ---------- layer 0, gate-at-a-time (i,f,g,o torch order; rows g=2) ----------
        {
            float gg[5]; L0_GATE(gg, 2);
            #pragma unroll
            for (int k = 0; k < 5; ++k) gg[k] = fast_tanh(gg[k]);
            float ii[5]; L0_GATE(ii, 0);
            #pragma unroll
            for (int k = 0; k < 5; ++k) ii[k] = fast_sigmoid(ii[k]) * gg[k];
            float ff[5]; L0_GATE(ff, 1);
            #pragma unroll
            for (int k = 0; k < 5; ++k) c0[k] = fast_sigmoid(ff[k])*c0[k] + ii[k];
            float oo[5]; L0_GATE(oo, 3);
            float hn[5];
            #pragma unroll
            for (int k = 0; k < 5; ++k) hn[k] = fast_sigmoid(oo[k]) * fast_tanh(c0[k]);
            #pragma unroll
            for (int k = 0; k < 5; ++k) { hP0[k] = __shfl_xor(hn[k], 1); hO0[k] = hn[k]; }
        }

        // ---------- layer 1 ----------
        {
            float gg[5]; L1_GATE(gg, 2);
            #pragma unroll
            for (int k = 0; k < 5; ++k) gg[k] = fast_tanh(gg[k]);
            float ii[5]; L1_GATE(ii, 0);
            #pragma unroll
            for (int k = 0; k < 5; ++k) ii[k] = fast_sigmoid(ii[k]) * gg[k];
            float ff[5]; L1_GATE(ff, 1);
            #pragma unroll
            for (int k = 0; k < 5; ++k) c1[k] = fast_sigmoid(ff[k])*c1[k] + ii[k];
            float oo[5]; L1_GATE(oo, 3);
            float hn[5];
            #pragma unroll
            for (int k = 0; k < 5; ++k) hn[k] = fast_sigmoid(oo[k]) * fast_tanh(c1[k]);
            #pragma unroll
            for (int k = 0; k < 5; ++k) { hP1[k] = __shfl_xor(hn[k], 1); hO1[k] = hn[k]; }
        }

        // one barrier per iteration: drains prefetch DMA (had full compute
        // phase to land) and protects the buffer swap
        __syncthreads();
    }

    // ---------- classifier: thread writes outputs ubase..ubase+4 ----------
    if (sample < B) {
        #pragma unroll
        for (int k = 0; k < 5; ++k) {
            const int o = ubase + k;
            float a = s_bcls[o];
            const float* wc = &s_wcls[(par*10 + o)*WLD];
            #pragma unroll
            for (int j = 0; j < 5; ++j) a += hO1[j]*wc[j] + hP1[j]*wc[5+j];
            out[(size_t)sample*10 + o] = a;
        }
    }
}

extern "C" void kernel_launch(void* const* d_in, const int* in_sizes, int n_in,
                              void* d_out, int out_size, void* d_ws, size_t ws_size,
                              hipStream_t stream) {
    const float* x     = (const float*)d_in[0];
    const float* w_ih0 = (const float*)d_in[1];
    const float* w_hh0 = (const float*)d_in[2];
    const float* b_ih0 = (const float*)d_in[3];
    const float* b_hh0 = (const float*)d_in[4];
    const float* w_ih1 = (const float*)d_in[5];
    const float* w_hh1 = (const float*)d_in[6];
    const float* b_ih1 = (const float*)d_in[7];
    const float* b_hh1 = (const float*)d_in[8];
    const float* w_cls = (const float*)d_in[9];
    const float* b_cls = (const float*)d_in[10];
    float* out = (float*)d_out;

    const int B = in_sizes[0] / (TSTEPS * DDIM);   // 32768
    const int grid = (2 * B + 255) / 256;          // 256 blocks, 128 samples each

    hipLaunchKernelGGL(lstm2_cls_kernel, dim3(grid), dim3(256), 0, stream,
                       x, w_ih0, w_hh0, b_ih0, b_hh0,
                       w_ih1, w_hh1, b_ih1, b_hh1,
                       w_cls, b_cls, out, B);
}

// Round 3
// 492.024 us; speedup vs baseline: 2.8040x; 1.1917x over previous
//
#include <hip/hip_runtime.h>

// MNIST_RNN: 2-layer LSTM (H=10, D=28, T=28) + classifier, fp32.
// R3: one THREAD per sample => all weight/bias indices are wave-uniform =>
// compiler emits scalar s_load for every weight (scalar pipe, SGPR operand
// in v_fma) -- eliminates the ~300 ds_read/t per thread that serialized R2
// at 1 wave/SIMD (VALUBusy 20%, 40.9k cyc/t measured vs 36k cyc of serial
// LDS latency). Only LDS use left: double-buffered x tile via
// global_load_lds (7 ds_read_b128 per t). No shuffles, no h exchange.
// Block=64 (1 wave), grid=512 -> 2 blocks/CU.

#define HDIM 10
#define DDIM 28
#define TSTEPS 28

typedef const __attribute__((address_space(1))) unsigned int gu32;
typedef __attribute__((address_space(3))) unsigned int lu32;

__device__ __forceinline__ void gld_lds16(const float* g, float4* l) {
    __builtin_amdgcn_global_load_lds((gu32*)g, (lu32*)l, 16, 0, 0);
}

__device__ __forceinline__ float fast_sigmoid(float v) {
    return __builtin_amdgcn_rcpf(1.0f + __expf(-v));
}
__device__ __forceinline__ float fast_tanh(float v) {
    return 2.0f * __builtin_amdgcn_rcpf(1.0f + __expf(-2.0f * v)) - 1.0f;
}

__global__ __launch_bounds__(64) void lstm2_cls_kernel(
    const float* __restrict__ x,
    const float* __restrict__ w_ih0, const float* __restrict__ w_hh0,
    const float* __restrict__ b_ih0, const float* __restrict__ b_hh0,
    const float* __restrict__ w_ih1, const float* __restrict__ w_hh1,
    const float* __restrict__ b_ih1, const float* __restrict__ b_hh1,
    const float* __restrict__ w_cls, const float* __restrict__ b_cls,
    float* __restrict__ out)
{
    __shared__ float4 sx[2][7 * 64];   // [buf][v*64 + lane], 14,336 B

    const int tid = threadIdx.x;
    const int sample = blockIdx.x * 64 + tid;
    const float* xs = x + (size_t)sample * (TSTEPS * DDIM);

    // preload t=0 tile (fire-and-forget DMA; lane offset = tid*16 matches
    // the wave-uniform-base + lane*16 deposit rule)
    #pragma unroll
    for (int k = 0; k < 7; ++k) gld_lds16(xs + 4 * k, &sx[0][k * 64 + tid]);

    float h0[HDIM], c0[HDIM], h1[HDIM], c1[HDIM];
    #pragma unroll
    for (int u = 0; u < HDIM; ++u) { h0[u] = c0[u] = h1[u] = c1[u] = 0.0f; }

    __syncthreads();   // drains t=0 DMA (vmcnt) for the single wave

    #pragma unroll 1
    for (int t = 0; t < TSTEPS; ++t) {
        const int cur = t & 1;

        // prefetch t+1 into the other buffer before touching compute
        if (t + 1 < TSTEPS) {
            const float* xn = xs + (t + 1) * DDIM;
            #pragma unroll
            for (int k = 0; k < 7; ++k)
                gld_lds16(xn + 4 * k, &sx[cur ^ 1][k * 64 + tid]);
        }

        // x row for this sample: 7x ds_read_b128
        float xr[DDIM];
        {
            #pragma unroll
            for (int k = 0; k < 7; ++k) {
                const float4 q = sx[cur][k * 64 + tid];
                xr[4*k+0] = q.x; xr[4*k+1] = q.y; xr[4*k+2] = q.z; xr[4*k+3] = q.w;
            }
        }

        // ---------------- layer 0 (gates rows: i=0..9, f=10..19, g=20..29, o=30..39)
        {
            float gg[HDIM];
            #pragma unroll
            for (int u = 0; u < HDIM; ++u) {           // g gate (tanh)
                const int r = 20 + u;
                float a = b_ih0[r] + b_hh0[r];
                #pragma unroll
                for (int d = 0; d < DDIM; ++d) a += xr[d] * w_ih0[r * DDIM + d];
                #pragma unroll
                for (int j = 0; j < HDIM; ++j) a += h0[j] * w_hh0[r * HDIM + j];
                gg[u] = fast_tanh(a);
            }
            #pragma unroll
            for (int u = 0; u < HDIM; ++u) {           // i gate -> ig = si*tg
                const int r = u;
                float a = b_ih0[r] + b_hh0[r];
                #pragma unroll
                for (int d = 0; d < DDIM; ++d) a += xr[d] * w_ih0[r * DDIM + d];
                #pragma unroll
                for (int j = 0; j < HDIM; ++j) a += h0[j] * w_hh0[r * HDIM + j];
                gg[u] *= fast_sigmoid(a);
            }
            #pragma unroll
            for (int u = 0; u < HDIM; ++u) {           // f gate -> c update
                const int r = 10 + u;
                float a = b_ih0[r] + b_hh0[r];
                #pragma unroll
                for (int d = 0; d < DDIM; ++d) a += xr[d] * w_ih0[r * DDIM + d];
                #pragma unroll
                for (int j = 0; j < HDIM; ++j) a += h0[j] * w_hh0[r * HDIM + j];
                c0[u] = fast_sigmoid(a) * c0[u] + gg[u];
            }
            float oo[HDIM];
            #pragma unroll
            for (int u = 0; u < HDIM; ++u) {           // o gate raw (h0 still old!)
                const int r = 30 + u;
                float a = b_ih0[r] + b_hh0[r];
                #pragma unroll
                for (int d = 0; d < DDIM; ++d) a += xr[d] * w_ih0[r * DDIM + d];
                #pragma unroll
                for (int j = 0; j < HDIM; ++j) a += h0[j] * w_hh0[r * HDIM + j];
                oo[u] = a;
            }
            #pragma unroll
            for (int u = 0; u < HDIM; ++u)
                h0[u] = fast_sigmoid(oo[u]) * fast_tanh(c0[u]);
        }

        // ---------------- layer 1 (input = new h0, state h1/c1)
        {
            float gg[HDIM];
            #pragma unroll
            for (int u = 0; u < HDIM; ++u) {
                const int r = 20 + u;
                float a = b_ih1[r] + b_hh1[r];
                #pragma unroll
                for (int j = 0; j < HDIM; ++j) a += h0[j] * w_ih1[r * HDIM + j];
                #pragma unroll
                for (int j = 0; j < HDIM; ++j) a += h1[j] * w_hh1[r * HDIM + j];
                gg[u] = fast_tanh(a);
            }
            #pragma unroll
            for (int u = 0; u < HDIM; ++u) {
                const int r = u;
                float a = b_ih1[r] + b_hh1[r];
                #pragma unroll
                for (int j = 0; j < HDIM; ++j) a += h0[j] * w_ih1[r * HDIM + j];
                #pragma unroll
                for (int j = 0; j < HDIM; ++j) a += h1[j] * w_hh1[r * HDIM + j];
                gg[u] *= fast_sigmoid(a);
            }
            #pragma unroll
            for (int u = 0; u < HDIM; ++u) {
                const int r = 10 + u;
                float a = b_ih1[r] + b_hh1[r];
                #pragma unroll
                for (int j = 0; j < HDIM; ++j) a += h0[j] * w_ih1[r * HDIM + j];
                #pragma unroll
                for (int j = 0; j < HDIM; ++j) a += h1[j] * w_hh1[r * HDIM + j];
                c1[u] = fast_sigmoid(a) * c1[u] + gg[u];
            }
            float oo[HDIM];
            #pragma unroll
            for (int u = 0; u < HDIM; ++u) {
                const int r = 30 + u;
                float a = b_ih1[r] + b_hh1[r];
                #pragma unroll
                for (int j = 0; j < HDIM; ++j) a += h0[j] * w_ih1[r * HDIM + j];
                #pragma unroll
                for (int j = 0; j < HDIM; ++j) a += h1[j] * w_hh1[r * HDIM + j];
                oo[u] = a;
            }
            #pragma unroll
            for (int u = 0; u < HDIM; ++u)
                h1[u] = fast_sigmoid(oo[u]) * fast_tanh(c1[u]);
        }

        __syncthreads();   // drains prefetch DMA + protects buffer swap
    }

    // ---------------- classifier ----------------
    #pragma unroll
    for (int o = 0; o < 10; ++o) {
        float a = b_cls[o];
        #pragma unroll
        for (int j = 0; j < HDIM; ++j) a += h1[j] * w_cls[o * HDIM + j];
        out[(size_t)sample * 10 + o] = a;
    }
}

extern "C" void kernel_launch(void* const* d_in, const int* in_sizes, int n_in,
                              void* d_out, int out_size, void* d_ws, size_t ws_size,
                              hipStream_t stream) {
    const float* x     = (const float*)d_in[0];
    const float* w_ih0 = (const float*)d_in[1];
    const float* w_hh0 = (const float*)d_in[2];
    const float* b_ih0 = (const float*)d_in[3];
    const float* b_hh0 = (const float*)d_in[4];
    const float* w_ih1 = (const float*)d_in[5];
    const float* w_hh1 = (const float*)d_in[6];
    const float* b_ih1 = (const float*)d_in[7];
    const float* b_hh1 = (const float*)d_in[8];
    const float* w_cls = (const float*)d_in[9];
    const float* b_cls = (const float*)d_in[10];
    float* out = (float*)d_out;

    const int B = in_sizes[0] / (TSTEPS * DDIM);   // 32768
    const int grid = B / 64;                       // 512 blocks of 1 wave

    hipLaunchKernelGGL(lstm2_cls_kernel, dim3(grid), dim3(64), 0, stream,
                       x, w_ih0, w_hh0, b_ih0, b_hh0,
                       w_ih1, w_hh1, b_ih1, b_hh1,
                       w_cls, b_cls, out);
}

// Round 4
// 354.489 us; speedup vs baseline: 3.8919x; 1.3880x over previous
//
#include <hip/hip_runtime.h>

// MNIST_RNN R4: gate-parallel waves. 8 waves x 64 samples per block; wave w
// owns 5 of the 40 gate rows (weights wave-uniform -> scalar s_load stream,
// ~300 floats/t/wave vs 2900 in R3). 512 blocks * 8 waves = 4096 waves =
// 4 waves/SIMD (R3: 0.5) to hide scalar-load latency, which was 27k of
// R3's 32.4k cyc/t. Gate activations exchanged via LDS [row][sample]
// (stride-1, conflict-free); every wave redundantly computes the c/h
// update for all 10 units so h stays in registers (no broadcast).
// 2 barriers/t. x staged via double-buffered global_load_lds as in R3.

#define HDIM 10
#define DDIM 28
#define TSTEPS 28

typedef const __attribute__((address_space(1))) unsigned int gu32;
typedef __attribute__((address_space(3))) unsigned int lu32;

__device__ __forceinline__ void gld_lds16(const float* g, float4* l) {
    __builtin_amdgcn_global_load_lds((gu32*)g, (lu32*)l, 16, 0, 0);
}

__device__ __forceinline__ float fast_sigmoid(float v) {
    return __builtin_amdgcn_rcpf(1.0f + __expf(-v));
}
__device__ __forceinline__ float fast_tanh(float v) {
    return 2.0f * __builtin_amdgcn_rcpf(1.0f + __expf(-2.0f * v)) - 1.0f;
}

__global__ __launch_bounds__(512, 4) void lstm2_cls_kernel(
    const float* __restrict__ x,
    const float* __restrict__ w_ih0, const float* __restrict__ w_hh0,
    const float* __restrict__ b_ih0, const float* __restrict__ b_hh0,
    const float* __restrict__ w_ih1, const float* __restrict__ w_hh1,
    const float* __restrict__ b_ih1, const float* __restrict__ b_hh1,
    const float* __restrict__ w_cls, const float* __restrict__ b_cls,
    float* __restrict__ out)
{
    __shared__ float4 sx[2][7 * 64];     // x tiles, transposed: slot v*64+lane
    __shared__ float g0[40 * 64];        // activated L0 gates [row][sample]
    __shared__ float g1[40 * 64];        // activated L1 gates [row][sample]

    const int tid  = threadIdx.x;
    const int lane = tid & 63;
    const int wid  = __builtin_amdgcn_readfirstlane(tid >> 6);  // uniform!
    const int b0   = blockIdx.x * 64;
    const int sample = b0 + lane;

    const int q     = wid >> 1;              // gate: 0=i 1=f 2=g 3=o
    const int rbase = q * 10 + (wid & 1) * 5; // this wave's 5 rows
    const bool is_g = (q == 2);              // tanh gate

    const float* xs = x + (size_t)sample * (TSTEPS * DDIM);

    // DMA t=0 tile: wave w deposits float4 column w for all 64 samples
    if (wid < 7) gld_lds16(xs + 4 * wid, &sx[0][wid * 64 + lane]);

    float h0[HDIM], c0[HDIM], h1[HDIM], c1[HDIM];
    #pragma unroll
    for (int u = 0; u < HDIM; ++u) { h0[u] = c0[u] = h1[u] = c1[u] = 0.0f; }

    __syncthreads();   // drain t=0 DMA

    #pragma unroll 1
    for (int t = 0; t < TSTEPS; ++t) {
        const int cur = t & 1;

        // prefetch t+1 (fire-and-forget; drained by this iter's 2nd barrier)
        if (t + 1 < TSTEPS && wid < 7)
            gld_lds16(xs + (t + 1) * DDIM + 4 * wid, &sx[cur ^ 1][wid * 64 + lane]);

        // x row for this lane's sample (7x ds_read_b128, conflict-free)
        float xr[DDIM];
        #pragma unroll
        for (int v = 0; v < 7; ++v) {
            const float4 qv = sx[cur][v * 64 + lane];
            xr[4*v+0] = qv.x; xr[4*v+1] = qv.y; xr[4*v+2] = qv.z; xr[4*v+3] = qv.w;
        }

        // ---- P1/L0: this wave's 5 rows of layer0 pre-activations ----
        {
            float a[5];
            #pragma unroll
            for (int k = 0; k < 5; ++k) {
                const int r = rbase + k;
                float acc = b_ih0[r] + b_hh0[r];
                const float* wi = w_ih0 + r * DDIM;
                #pragma unroll
                for (int d = 0; d < DDIM; ++d) acc += xr[d] * wi[d];
                const float* wh = w_hh0 + r * HDIM;
                #pragma unroll
                for (int j = 0; j < HDIM; ++j) acc += h0[j] * wh[j];
                a[k] = acc;
            }
            #pragma unroll
            for (int k = 0; k < 5; ++k) {
                const float v = is_g ? fast_tanh(a[k]) : fast_sigmoid(a[k]);
                g0[(rbase + k) * 64 + lane] = v;
            }
        }
        __syncthreads();   // BAR-A: all L0 gates visible

        // ---- P2/L0: redundant c0/h0 update (all units, per-wave copy) ----
        #pragma unroll
        for (int u = 0; u < HDIM; ++u) {
            const float iv = g0[(     u) * 64 + lane];
            const float fv = g0[(10 + u) * 64 + lane];
            const float gv = g0[(20 + u) * 64 + lane];
            const float ov = g0[(30 + u) * 64 + lane];
            const float c  = fv * c0[u] + iv * gv;
            c0[u] = c;
            h0[u] = ov * fast_tanh(c);
        }

        // ---- P1/L1: this wave's 5 rows of layer1 pre-activations ----
        {
            float a[5];
            #pragma unroll
            for (int k = 0; k < 5; ++k) {
                const int r = rbase + k;
                float acc = b_ih1[r] + b_hh1[r];
                const float* wi = w_ih1 + r * HDIM;
                #pragma unroll
                for (int j = 0; j < HDIM; ++j) acc += h0[j] * wi[j];
                const float* wh = w_hh1 + r * HDIM;
                #pragma unroll
                for (int j = 0; j < HDIM; ++j) acc += h1[j] * wh[j];
                a[k] = acc;
            }
            #pragma unroll
            for (int k = 0; k < 5; ++k) {
                const float v = is_g ? fast_tanh(a[k]) : fast_sigmoid(a[k]);
                g1[(rbase + k) * 64 + lane] = v;
            }
        }
        __syncthreads();   // BAR-B: all L1 gates visible; also drains DMA

        // ---- P2/L1: redundant c1/h1 update ----
        #pragma unroll
        for (int u = 0; u < HDIM; ++u) {
            const float iv = g1[(     u) * 64 + lane];
            const float fv = g1[(10 + u) * 64 + lane];
            const float gv = g1[(20 + u) * 64 + lane];
            const float ov = g1[(30 + u) * 64 + lane];
            const float c  = fv * c1[u] + iv * gv;
            c1[u] = c;
            h1[u] = ov * fast_tanh(c);
        }
    }

    // ---- classifier: waves 0,1 each produce 5 outputs per sample ----
    if (wid < 2) {
        #pragma unroll
        for (int k = 0; k < 5; ++k) {
            const int o = wid * 5 + k;
            float a = b_cls[o];
            const float* wc = w_cls + o * HDIM;
            #pragma unroll
            for (int j = 0; j < HDIM; ++j) a += h1[j] * wc[j];
            out[(size_t)sample * 10 + o] = a;
        }
    }
}

extern "C" void kernel_launch(void* const* d_in, const int* in_sizes, int n_in,
                              void* d_out, int out_size, void* d_ws, size_t ws_size,
                              hipStream_t stream) {
    const float* x     = (const float*)d_in[0];
    const float* w_ih0 = (const float*)d_in[1];
    const float* w_hh0 = (const float*)d_in[2];
    const float* b_ih0 = (const float*)d_in[3];
    const float* b_hh0 = (const float*)d_in[4];
    const float* w_ih1 = (const float*)d_in[5];
    const float* w_hh1 = (const float*)d_in[6];
    const float* b_ih1 = (const float*)d_in[7];
    const float* b_hh1 = (const float*)d_in[8];
    const float* w_cls = (const float*)d_in[9];
    const float* b_cls = (const float*)d_in[10];
    float* out = (float*)d_out;

    const int B = in_sizes[0] / (TSTEPS * DDIM);   // 32768
    const int grid = B / 64;                       // 512 blocks (2/CU), 8 waves each

    hipLaunchKernelGGL(lstm2_cls_kernel, dim3(grid), dim3(512), 0, stream,
                       x, w_ih0, w_hh0, b_ih0, b_hh0,
                       w_ih1, w_hh1, b_ih1, b_hh1,
                       w_cls, b_cls, out);
}